// Round 2
// baseline (232.014 us; speedup 1.0000x reference)
//
#include <hip/hip_runtime.h>

// RY(theta) single-qubit gate on batched state vector.
// state: [B=32, 2^20] fp32. Target qubit q (static=3) maps to flat-index
// bit (20-1-q) = 16, i.e. element stride 2^16. Butterfly per pair:
//   y0 = c*x0 - s*x1 ; y1 = s*x0 + c*x1 ; t=theta/2, c=cos t, s=sin t.
// Memory-bound: 256 MiB total traffic -> ~43 us floor at 6.29 TB/s (m13
// float4-copy ceiling; traffic here is copy-shaped).
//
// R4: A/B experiment — remove ALL nontemporal hints (single-variable vs R3).
// The proven-fast paths on gfx950 (harness fill 6.7 TB/s, float4-copy
// 6.29 TB/s) use plain cached accesses; NT was added in a prior session
// without an isolated A/B. Keep the R3 wave-dense layout: each wave owns a
// contiguous 512-float lower chunk (lane l -> float4 at 4*l and 4*l+256),
// partners at +stride. Every VMEM instruction is a dense, line-aligned
// 1 KiB per wave. 16 elems/thread (4 loads + 4 stores in flight).

typedef float floatx4 __attribute__((ext_vector_type(4)));

__global__ __launch_bounds__(256) void ry_gate_kernel(
    const float* __restrict__ in,
    const float* __restrict__ theta,
    const int*   __restrict__ qubit,
    float*       __restrict__ out,
    unsigned int n_waves)   // each wave handles 512 lower + 512 upper floats
{
    const unsigned int tid  = blockIdx.x * blockDim.x + threadIdx.x;
    const unsigned int wv   = tid >> 6;           // global wave index
    const unsigned int lane = threadIdx.x & 63u;
    if (wv >= n_waves) return;

    // n = 20 total qubits (static per reference); target bit = 19 - qubit.
    const int shift = 19 - qubit[0];
    const unsigned int stride = 1u << shift;      // element stride (65536 for q=3)
    const unsigned int mask   = stride - 1u;

    float t = theta[0] * 0.5f;
    float s, c;
    sincosf(t, &s, &c);

    // Wave-contiguous lower-half chunk: elements [wv*512, wv*512+512).
    // Requires stride >= 512 (qubit <= 10 at n=20; qubit=3 here), so the
    // chunk lies inside one splice window and stays contiguous after the
    // bit-insert.
    const unsigned int e0 = wv * 512u + lane * 4u;
    const unsigned int i0 = (e0 & mask) | ((e0 & ~mask) << 1);  // lower, chunk A
    const unsigned int j0 = i0 + 256u;                          // lower, chunk B
    const unsigned int i1 = i0 + stride;                        // upper, chunk A
    const unsigned int j1 = j0 + stride;                        // upper, chunk B

    floatx4 a0 = *reinterpret_cast<const floatx4*>(in + i0);
    floatx4 a1 = *reinterpret_cast<const floatx4*>(in + j0);
    floatx4 b0 = *reinterpret_cast<const floatx4*>(in + i1);
    floatx4 b1 = *reinterpret_cast<const floatx4*>(in + j1);

    floatx4 y00 = c * a0 - s * b0;
    floatx4 y01 = c * a1 - s * b1;
    floatx4 y10 = s * a0 + c * b0;
    floatx4 y11 = s * a1 + c * b1;

    *reinterpret_cast<floatx4*>(out + i0) = y00;
    *reinterpret_cast<floatx4*>(out + j0) = y01;
    *reinterpret_cast<floatx4*>(out + i1) = y10;
    *reinterpret_cast<floatx4*>(out + j1) = y11;
}

// Scalar fallback (any qubit, incl. stride<512). Not used for qubit=3.
__global__ __launch_bounds__(256) void ry_gate_kernel_scalar(
    const float* __restrict__ in,
    const float* __restrict__ theta,
    const int*   __restrict__ qubit,
    float*       __restrict__ out,
    unsigned int n_pairs)
{
    unsigned int p = blockIdx.x * blockDim.x + threadIdx.x;
    if (p >= n_pairs) return;

    const int shift = 19 - qubit[0];
    const unsigned int stride = 1u << shift;
    const unsigned int mask   = stride - 1u;

    float t = theta[0] * 0.5f;
    float s, c;
    sincosf(t, &s, &c);

    unsigned int i0 = (p & mask) | ((p & ~mask) << 1);
    unsigned int i1 = i0 + stride;

    float x0 = in[i0], x1 = in[i1];
    out[i0] = c * x0 - s * x1;
    out[i1] = s * x0 + c * x1;
}

extern "C" void kernel_launch(void* const* d_in, const int* in_sizes, int n_in,
                              void* d_out, int out_size, void* d_ws, size_t ws_size,
                              hipStream_t stream)
{
    const float* state = (const float*)d_in[0];
    const float* theta = (const float*)d_in[1];
    const int*   qubit = (const int*)d_in[2];
    float*       out   = (float*)d_out;

    const unsigned int n_total = (unsigned int)in_sizes[0];   // 32 * 2^20
    const unsigned int n_waves = n_total / 1024u;             // 1024 elems/wave
    const unsigned int n_thr   = n_waves * 64u;
    const int block = 256;
    const unsigned int grid = (n_thr + block - 1) / block;
    ry_gate_kernel<<<grid, block, 0, stream>>>(state, theta, qubit, out, n_waves);
}

// Round 3
// 225.118 us; speedup vs baseline: 1.0306x; 1.0306x over previous
//
#include <hip/hip_runtime.h>

// RY(theta) single-qubit gate on batched state vector.
// state: [B=32, 2^20] fp32. Target qubit q (static=3) maps to flat-index
// bit (20-1-q) = 16, i.e. element stride 2^16. Butterfly per pair:
//   y0 = c*x0 - s*x1 ; y1 = s*x0 + c*x1 ; t=theta/2, c=cos t, s=sin t.
// Memory-bound: 256 MiB total traffic -> ~43 us floor at 6.3 TB/s.
//
// R5: persistent grid-stride + software pipeline. R4 counters showed ideal
// traffic (FETCH 64Mi w/ LLC hits, WRITE 128Mi exact) but only 3.4 TB/s:
// one-shot waves (8 KiB each, 4 loads -> drain -> 4 stores -> exit) are
// issue/latency-limited, not traffic-limited. Now: 2048 blocks (8/CU, full
// 8-wave/SIMD TLP), each wave loops over 4 chunks with next-chunk loads
// issued BEFORE current-chunk stores, so the VMEM queue never drains
// (compiler waits vmcnt(4): current data ready, next loads + prior stores
// still in flight). NT hints restored (R4 A/B: removing them cost ~8 us).
// Wave-dense layout kept from R3: wave owns a contiguous 512-float lower
// chunk; lane l -> float4 at 4*l and 4*l+256; partners at +stride. Every
// VMEM instruction is dense, line-aligned 1 KiB/wave.

typedef float floatx4 __attribute__((ext_vector_type(4)));

__global__ __launch_bounds__(256) void ry_gate_kernel(
    const float* __restrict__ in,
    const float* __restrict__ theta,
    const int*   __restrict__ qubit,
    float*       __restrict__ out,
    unsigned int n_chunks)   // chunks of 512 lower + 512 upper floats
{
    const unsigned int n_act_waves = (gridDim.x * blockDim.x) >> 6;
    const unsigned int tid  = blockIdx.x * blockDim.x + threadIdx.x;
    const unsigned int lane = threadIdx.x & 63u;
    unsigned int chunk = tid >> 6;
    if (chunk >= n_chunks) return;

    // n = 20 total qubits (static per reference); target bit = 19 - qubit.
    const int shift = 19 - qubit[0];
    const unsigned int stride = 1u << shift;      // element stride (65536 for q=3)
    const unsigned int mask   = stride - 1u;

    float t = theta[0] * 0.5f;
    float s, c;
    sincosf(t, &s, &c);

    const unsigned int loff = lane * 4u;

    // Chunk lies inside one splice window iff stride >= 512 (qubit <= 10
    // at n=20; qubit=3 here), so after bit-insert it stays contiguous.
    unsigned int e0 = chunk * 512u + loff;
    unsigned int i0 = (e0 & mask) | ((e0 & ~mask) << 1);  // lower, sub A
    unsigned int j0 = i0 + 256u;                          // lower, sub B
    unsigned int i1 = i0 + stride;                        // upper, sub A
    unsigned int j1 = j0 + stride;                        // upper, sub B

    floatx4 a0 = __builtin_nontemporal_load(reinterpret_cast<const floatx4*>(in + i0));
    floatx4 a1 = __builtin_nontemporal_load(reinterpret_cast<const floatx4*>(in + j0));
    floatx4 b0 = __builtin_nontemporal_load(reinterpret_cast<const floatx4*>(in + i1));
    floatx4 b1 = __builtin_nontemporal_load(reinterpret_cast<const floatx4*>(in + j1));

    for (;;) {
        const unsigned int next = chunk + n_act_waves;
        const bool have_next = next < n_chunks;

        unsigned int ni0 = 0, nj0 = 0, ni1 = 0, nj1 = 0;
        floatx4 na0, na1, nb0, nb1;
        if (have_next) {
            unsigned int ne = next * 512u + loff;
            ni0 = (ne & mask) | ((ne & ~mask) << 1);
            nj0 = ni0 + 256u;
            ni1 = ni0 + stride;
            nj1 = nj0 + stride;
            na0 = __builtin_nontemporal_load(reinterpret_cast<const floatx4*>(in + ni0));
            na1 = __builtin_nontemporal_load(reinterpret_cast<const floatx4*>(in + nj0));
            nb0 = __builtin_nontemporal_load(reinterpret_cast<const floatx4*>(in + ni1));
            nb1 = __builtin_nontemporal_load(reinterpret_cast<const floatx4*>(in + nj1));
        }

        floatx4 y00 = c * a0 - s * b0;
        floatx4 y01 = c * a1 - s * b1;
        floatx4 y10 = s * a0 + c * b0;
        floatx4 y11 = s * a1 + c * b1;

        __builtin_nontemporal_store(y00, reinterpret_cast<floatx4*>(out + i0));
        __builtin_nontemporal_store(y01, reinterpret_cast<floatx4*>(out + j0));
        __builtin_nontemporal_store(y10, reinterpret_cast<floatx4*>(out + i1));
        __builtin_nontemporal_store(y11, reinterpret_cast<floatx4*>(out + j1));

        if (!have_next) break;
        chunk = next;
        i0 = ni0; j0 = nj0; i1 = ni1; j1 = nj1;
        a0 = na0; a1 = na1; b0 = nb0; b1 = nb1;
    }
}

// Scalar fallback (any qubit, incl. stride<512). Not used for qubit=3.
__global__ __launch_bounds__(256) void ry_gate_kernel_scalar(
    const float* __restrict__ in,
    const float* __restrict__ theta,
    const int*   __restrict__ qubit,
    float*       __restrict__ out,
    unsigned int n_pairs)
{
    unsigned int p = blockIdx.x * blockDim.x + threadIdx.x;
    if (p >= n_pairs) return;

    const int shift = 19 - qubit[0];
    const unsigned int stride = 1u << shift;
    const unsigned int mask   = stride - 1u;

    float t = theta[0] * 0.5f;
    float s, c;
    sincosf(t, &s, &c);

    unsigned int i0 = (p & mask) | ((p & ~mask) << 1);
    unsigned int i1 = i0 + stride;

    float x0 = in[i0], x1 = in[i1];
    out[i0] = c * x0 - s * x1;
    out[i1] = s * x0 + c * x1;
}

extern "C" void kernel_launch(void* const* d_in, const int* in_sizes, int n_in,
                              void* d_out, int out_size, void* d_ws, size_t ws_size,
                              hipStream_t stream)
{
    const float* state = (const float*)d_in[0];
    const float* theta = (const float*)d_in[1];
    const int*   qubit = (const int*)d_in[2];
    float*       out   = (float*)d_out;

    const unsigned int n_total  = (unsigned int)in_sizes[0];  // 32 * 2^20
    const unsigned int n_chunks = n_total / 1024u;            // 1024 elems/chunk
    const int block = 256;
    // Persistent-style: 2048 blocks = 8/CU, 8 waves/SIMD; each wave
    // grid-strides over n_chunks / 8192 = 4 chunks (for the 32*2^20 shape).
    unsigned int grid = (n_chunks * 64u + block - 1) / block;
    if (grid > 2048u) grid = 2048u;
    ry_gate_kernel<<<grid, block, 0, stream>>>(state, theta, qubit, out, n_chunks);
}